// Round 5
// baseline (175.762 us; speedup 1.0000x reference)
//
#include <hip/hip_runtime.h>

#define NPTS   32768
#define NCODES 1024
#define DIM    256
#define HWSZ   1024
#define CHW    (DIM*HWSZ)      // 262144
#define QSZ    8388608         // B*C*H*W

typedef __attribute__((ext_vector_type(8))) short short8;   // 8 bf16 = 4 VGPRs
typedef __attribute__((ext_vector_type(4))) float f32x4;

// async global->LDS, 16B per lane; dest = wave-uniform base + lane*16
__device__ __forceinline__ void gload16(const void* g, void* l) {
    __builtin_amdgcn_global_load_lds((const __attribute__((address_space(1))) void*)g,
                                     (__attribute__((address_space(3))) void*)l,
                                     16, 0, 0);
}

__device__ __forceinline__ unsigned bf16_rne(float f) {
    unsigned u = __float_as_uint(f);
    return (u + 0x7fffu + ((u >> 16) & 1u)) >> 16;
}

// ---- fused prep: blocks 0..1023 = z -> Xh/Xl transpose+split;
//                  blocks 1024..1279 = emb -> Eh/El + e2 ----
__global__ void k_prep(const float* __restrict__ z, const float* __restrict__ emb,
                       short* __restrict__ Xh, short* __restrict__ Xl,
                       short* __restrict__ Eh, short* __restrict__ El,
                       float* __restrict__ e2) {
    int tid = threadIdx.x;
    if (blockIdx.x >= 1024) {
        // --- emb row -> Eh/El bf16 split + e2 (fp64). 1 wave per row. ---
        int lane = tid & 63, w = tid >> 6;
        int k = (blockIdx.x - 1024) * 4 + w;
        const float4 v = *reinterpret_cast<const float4*>(emb + k * DIM + lane * 4);
        float f[4] = {v.x, v.y, v.z, v.w};
        short h[4], l[4];
        double s = 0.0;
        #pragma unroll
        for (int i = 0; i < 4; ++i) {
            unsigned hb = bf16_rne(f[i]);
            float hf = __uint_as_float(hb << 16);
            h[i] = (short)hb;
            l[i] = (short)bf16_rne(f[i] - hf);
            s += (double)f[i] * f[i];
        }
        *reinterpret_cast<short4*>(Eh + k * DIM + lane * 4) = make_short4(h[0], h[1], h[2], h[3]);
        *reinterpret_cast<short4*>(El + k * DIM + lane * 4) = make_short4(l[0], l[1], l[2], l[3]);
        #pragma unroll
        for (int m = 32; m >= 1; m >>= 1) s += __shfl_xor(s, m);
        if (lane == 0) e2[k] = (float)s;
        return;
    }
    // --- z (b,c,hw) -> Xh/Xl row-major (n,c) bf16 hi/lo; 16B stores ---
    __shared__ float T[64][33];          // [c_local][hw_local], pad: <=2-way banks
    int blk = blockIdx.x;
    int b  = blk >> 5;
    int ht = blk & 31;
    int hw0 = ht * 32;
    int n0  = b * HWSZ + hw0;
    int hq = tid & 7, cr = tid >> 3;     // read map: 32 c-rows x 8 float4 lanes
    int wp = tid >> 3, wc = tid & 7;     // write map: 32 points x 8 channel-octets
    const float* zp = z + b * CHW;
    #pragma unroll
    for (int cc = 0; cc < 4; ++cc) {
        int c0 = cc * 64;
        if (cc) __syncthreads();
        #pragma unroll
        for (int p = 0; p < 2; ++p) {
            int c = p * 32 + cr;
            float4 v = *reinterpret_cast<const float4*>(zp + (c0 + c) * HWSZ + hw0 + hq * 4);
            T[c][hq * 4 + 0] = v.x; T[c][hq * 4 + 1] = v.y;
            T[c][hq * 4 + 2] = v.z; T[c][hq * 4 + 3] = v.w;
        }
        __syncthreads();
        short8 hv, lv;
        #pragma unroll
        for (int k = 0; k < 8; ++k) {
            float f = T[wc * 8 + k][wp];
            unsigned hb = bf16_rne(f);
            float hf = __uint_as_float(hb << 16);
            hv[k] = (short)hb;
            lv[k] = (short)bf16_rne(f - hf);
        }
        *reinterpret_cast<short8*>(Xh + (n0 + wp) * DIM + c0 + wc * 8) = hv;
        *reinterpret_cast<short8*>(Xl + (n0 + wp) * DIM + c0 + wc * 8) = lv;
    }
}

// ---- fused split-bf16 MFMA distance GEMM + argmin over a 128-code tile ----
// Block 128 thr (2 waves). Block tile 128 pts x 128 codes; each wave owns
// 64 pts x ALL 128 codes (4 MFMA per ds_read, no cross-wave reduction).
// grid 2048: pt = blk&255, ct = blk>>8 -> 8 ct-blocks of a pt share blk%8 (XCD).
// LDS k-quad swizzle keyed on (row>>1)&3: staged via per-lane SOURCE k-offset
// permutation (global_load_lds can't scatter); frag reads land <=2-way banks.
__launch_bounds__(128, 2)
__global__ void k_dist(const short* __restrict__ Xh, const short* __restrict__ Xl,
                       const short* __restrict__ Eh, const short* __restrict__ El,
                       const float* __restrict__ e2, float* __restrict__ minv,
                       int* __restrict__ mini) {
    __shared__ __align__(16) short Ah[4096];   // [128 pts][32 k] (swizzled quads)
    __shared__ __align__(16) short Al[4096];
    __shared__ __align__(16) short Bh[4096];   // [128 codes][32 k]
    __shared__ __align__(16) short Bl[4096];

    const int tid = threadIdx.x;
    const int pt = blockIdx.x & 255;
    const int ct = blockIdx.x >> 8;
    const int n0 = pt * 128;
    const int c0 = ct * 128;

    const int w = tid >> 6, lane = tid & 63;
    const int m16 = lane & 15, quad = lane >> 4;

    f32x4 acc[4][8];
    #pragma unroll
    for (int i = 0; i < 4; ++i)
        #pragma unroll
        for (int j = 0; j < 8; ++j) acc[i][j] = (f32x4){0.f, 0.f, 0.f, 0.f};

    // staging: wave0 stages Ah+Bh, wave1 stages Al+Bl (8 gloads each side).
    // lane -> (row-in-16-group r4 = lane>>2, phys quad q = lane&3);
    // swizzle key s = (row>>1)&3 = (lane>>3)&3; source logical quad = (q-s)&3.
    const int r4  = lane >> 2;
    const int swz = (((lane & 3) - ((lane >> 3) & 3)) & 3) * 8;  // shorts
    const short* srcA = w ? Xl : Xh;
    const short* srcB = w ? El : Eh;
    char* dstA = (char*)(w ? Al : Ah);
    char* dstB = (char*)(w ? Bl : Bh);

    // frag-read swizzle: phys quad = (quad + (m16>>1)) & 3
    const int pq = ((quad + (m16 >> 1)) & 3) * 8;

    for (int t = 0; t < 8; ++t) {
        const int koff = t * 32 + swz;
        __syncthreads();
        #pragma unroll
        for (int g = 0; g < 8; ++g) {
            gload16(srcA + (n0 + g * 16 + r4) * DIM + koff, dstA + g * 1024);
            gload16(srcB + (c0 + g * 16 + r4) * DIM + koff, dstB + g * 1024);
        }
        __syncthreads();                 // compiler drains vmcnt before barrier

        short8 ah[4], al[4];
        #pragma unroll
        for (int i = 0; i < 4; ++i) {
            int ar = (w * 64 + i * 16 + m16) * 32 + pq;
            ah[i] = *(const short8*)&Ah[ar];
            al[i] = *(const short8*)&Al[ar];
        }
        #pragma unroll
        for (int j = 0; j < 8; ++j) {
            int br = (j * 16 + m16) * 32 + pq;
            short8 bh = *(const short8*)&Bh[br];
            short8 bl = *(const short8*)&Bl[br];
            #pragma unroll
            for (int i = 0; i < 4; ++i) {
                acc[i][j] = __builtin_amdgcn_mfma_f32_16x16x32_bf16(ah[i], bh, acc[i][j], 0, 0, 0);
                acc[i][j] = __builtin_amdgcn_mfma_f32_16x16x32_bf16(al[i], bh, acc[i][j], 0, 0, 0);
                acc[i][j] = __builtin_amdgcn_mfma_f32_16x16x32_bf16(ah[i], bl, acc[i][j], 0, 0, 0);
            }
        }
    }

    // dist = e2[code] - 2*dot ; C/D layout: col=lane&15 (code), row=quad*4+reg (pt)
    float ecol[8];
    #pragma unroll
    for (int j = 0; j < 8; ++j) ecol[j] = e2[c0 + j * 16 + m16];

    #pragma unroll
    for (int i = 0; i < 4; ++i) {
        #pragma unroll
        for (int rr = 0; rr < 4; ++rr) {
            float best = 3.4e38f; int bi = 0;
            #pragma unroll
            for (int j = 0; j < 8; ++j) {           // j ascending -> code ascending
                float d = fmaf(-2.f, acc[i][j][rr], ecol[j]);
                int code = c0 + j * 16 + m16;
                if (d < best) { best = d; bi = code; }
            }
            #pragma unroll
            for (int m = 1; m < 16; m <<= 1) {      // 16 lanes hold 16 codes of this pt
                float ov = __shfl_xor(best, m);
                int   oi = __shfl_xor(bi, m);
                if (ov < best || (ov == best && oi < bi)) { best = ov; bi = oi; }
            }
            if (m16 == 0) {
                int n = n0 + w * 64 + i * 16 + quad * 4 + rr;
                minv[ct * NPTS + n] = best;
                mini[ct * NPTS + n] = bi;
            }
        }
    }
}

// ---- fused: combine 8 code-tile winners + gather + write q/st/idx ----
// grid 1024 x 256; 32 points per block.
__global__ void k_out(const float* __restrict__ z, const float* __restrict__ emb,
                      const float* __restrict__ minv, const int* __restrict__ mini,
                      float* __restrict__ out) {
    __shared__ float Q[32][257];                    // [hw_local][c], pad: <=2-way banks
    __shared__ int sbi[32];
    int n0 = blockIdx.x * 32;
    int tid = threadIdx.x;
    if (tid < 32) {
        int n = n0 + tid;
        float bv = minv[n]; int bi = mini[n];
        #pragma unroll
        for (int g = 1; g < 8; ++g) {
            float v = minv[g * NPTS + n]; int ii = mini[g * NPTS + n];
            if (v < bv) { bv = v; bi = ii; }        // ascending groups -> first-min
        }
        sbi[tid] = bi;
        out[2 * QSZ + n] = (float)bi;               // idx as float
    }
    __syncthreads();
    {   // gather: 8 lanes x float4 cover one emb row 128B-contiguous per j
        int pt = tid >> 3, co = tid & 7;
        const float* ep = emb + sbi[pt] * DIM;
        #pragma unroll
        for (int j = 0; j < 8; ++j) {
            int c = j * 32 + co * 4;
            float4 v = *reinterpret_cast<const float4*>(ep + c);
            Q[pt][c] = v.x; Q[pt][c + 1] = v.y; Q[pt][c + 2] = v.z; Q[pt][c + 3] = v.w;
        }
    }
    __syncthreads();
    int hq = tid & 7, cr = tid >> 3;
    int b = n0 >> 10, hw0 = (n0 & 1023) + hq * 4;
    #pragma unroll
    for (int it = 0; it < 8; ++it) {
        int c = it * 32 + cr;
        int off = b * CHW + c * HWSZ + hw0;
        float4 zv = *reinterpret_cast<const float4*>(z + off);
        float4 q = make_float4(Q[hq * 4 + 0][c], Q[hq * 4 + 1][c],
                               Q[hq * 4 + 2][c], Q[hq * 4 + 3][c]);
        *reinterpret_cast<float4*>(out + off) = q;
        float4 st = make_float4((q.x - zv.x) + zv.x, (q.y - zv.y) + zv.y,
                                (q.z - zv.z) + zv.z, (q.w - zv.w) + zv.w);
        *reinterpret_cast<float4*>(out + QSZ + off) = st;
    }
}

extern "C" void kernel_launch(void* const* d_in, const int* in_sizes, int n_in,
                              void* d_out, int out_size, void* d_ws, size_t ws_size,
                              hipStream_t stream) {
    const float* z   = (const float*)d_in[0];
    const float* emb = (const float*)d_in[1];
    float* out = (float*)d_out;
    float* ws  = (float*)d_ws;

    // ws layout (floats): Eh[0,131072) El[131072,262144) e2[262144,263168)
    //                     minv[263168,525312) mini[525312,787456)
    short* Eh   = (short*)ws;
    short* El   = (short*)(ws + 131072);
    float* e2   = ws + 262144;
    float* minv = ws + 263168;
    int*   mini = (int*)(ws + 525312);

    // big X arrays live in d_out's q/st region (fully overwritten by k_out later)
    short* Xh = (short*)out;                 // 16.8 MB
    short* Xl = (short*)(out + 4194304);     // 16.8 MB

    hipLaunchKernelGGL(k_prep, dim3(1280), dim3(256), 0, stream, z, emb, Xh, Xl, Eh, El, e2);
    hipLaunchKernelGGL(k_dist, dim3(2048), dim3(128), 0, stream, Xh, Xl, Eh, El, e2, minv, mini);
    hipLaunchKernelGGL(k_out,  dim3(1024), dim3(256), 0, stream, z, emb, minv, mini, out);
}

// Round 6
// 166.501 us; speedup vs baseline: 1.0556x; 1.0556x over previous
//
#include <hip/hip_runtime.h>

#define NPTS   32768
#define NCODES 1024
#define DIM    256
#define HWSZ   1024
#define CHW    (DIM*HWSZ)      // 262144
#define QSZ    8388608         // B*C*H*W

typedef __attribute__((ext_vector_type(8))) short short8;   // 8 bf16 = 4 VGPRs
typedef __attribute__((ext_vector_type(4))) float f32x4;

// async global->LDS, 16B per lane; dest = wave-uniform base + lane*16
__device__ __forceinline__ void gload16(const void* g, void* l) {
    __builtin_amdgcn_global_load_lds((const __attribute__((address_space(1))) void*)g,
                                     (__attribute__((address_space(3))) void*)l,
                                     16, 0, 0);
}

__device__ __forceinline__ unsigned bf16_rne(float f) {
    unsigned u = __float_as_uint(f);
    return (u + 0x7fffu + ((u >> 16) & 1u)) >> 16;
}

// ---- fused prep: blocks 0..1023 = z -> Xh/Xl transpose+split;
//                  blocks 1024..1279 = emb -> Eh/El + e2 ----
__global__ void k_prep(const float* __restrict__ z, const float* __restrict__ emb,
                       short* __restrict__ Xh, short* __restrict__ Xl,
                       short* __restrict__ Eh, short* __restrict__ El,
                       float* __restrict__ e2) {
    int tid = threadIdx.x;
    if (blockIdx.x >= 1024) {
        // --- emb row -> Eh/El bf16 split + e2 (fp64). 1 wave per row. ---
        int lane = tid & 63, w = tid >> 6;
        int k = (blockIdx.x - 1024) * 4 + w;
        const float4 v = *reinterpret_cast<const float4*>(emb + k * DIM + lane * 4);
        float f[4] = {v.x, v.y, v.z, v.w};
        short h[4], l[4];
        double s = 0.0;
        #pragma unroll
        for (int i = 0; i < 4; ++i) {
            unsigned hb = bf16_rne(f[i]);
            float hf = __uint_as_float(hb << 16);
            h[i] = (short)hb;
            l[i] = (short)bf16_rne(f[i] - hf);
            s += (double)f[i] * f[i];
        }
        *reinterpret_cast<short4*>(Eh + k * DIM + lane * 4) = make_short4(h[0], h[1], h[2], h[3]);
        *reinterpret_cast<short4*>(El + k * DIM + lane * 4) = make_short4(l[0], l[1], l[2], l[3]);
        #pragma unroll
        for (int m = 32; m >= 1; m >>= 1) s += __shfl_xor(s, m);
        if (lane == 0) e2[k] = (float)s;
        return;
    }
    // --- z (b,c,hw) -> Xh/Xl row-major (n,c) bf16 hi/lo; 16B stores ---
    __shared__ float T[64][33];          // [c_local][hw_local], pad: <=2-way banks
    int blk = blockIdx.x;
    int b  = blk >> 5;
    int ht = blk & 31;
    int hw0 = ht * 32;
    int n0  = b * HWSZ + hw0;
    int hq = tid & 7, cr = tid >> 3;     // read map: 32 c-rows x 8 float4 lanes
    int wp = tid >> 3, wc = tid & 7;     // write map: 32 points x 8 channel-octets
    const float* zp = z + b * CHW;
    #pragma unroll
    for (int cc = 0; cc < 4; ++cc) {
        int c0 = cc * 64;
        if (cc) __syncthreads();
        #pragma unroll
        for (int p = 0; p < 2; ++p) {
            int c = p * 32 + cr;
            float4 v = *reinterpret_cast<const float4*>(zp + (c0 + c) * HWSZ + hw0 + hq * 4);
            T[c][hq * 4 + 0] = v.x; T[c][hq * 4 + 1] = v.y;
            T[c][hq * 4 + 2] = v.z; T[c][hq * 4 + 3] = v.w;
        }
        __syncthreads();
        short8 hv, lv;
        #pragma unroll
        for (int k = 0; k < 8; ++k) {
            float f = T[wc * 8 + k][wp];
            unsigned hb = bf16_rne(f);
            float hf = __uint_as_float(hb << 16);
            hv[k] = (short)hb;
            lv[k] = (short)bf16_rne(f - hf);
        }
        *reinterpret_cast<short8*>(Xh + (n0 + wp) * DIM + c0 + wc * 8) = hv;
        *reinterpret_cast<short8*>(Xl + (n0 + wp) * DIM + c0 + wc * 8) = lv;
    }
}

// ---- fused split-bf16 MFMA distance GEMM + argmin over a 128-code tile ----
// Round-4 structure (256 thr, 2x2 wave grid of 64x64 tiles, 48 MFMA/chunk)
// + round-5 bank-conflict swizzle (measured: conflicts -> 0):
//   staging permutes the SOURCE k-quad per lane (global_load_lds can't scatter),
//   frag reads use physical quad (quad + (m16>>1)) & 3  ->  <=2-way banks.
// grid 2048: pt = blk&255, ct = blk>>8 -> 8 ct-blocks of a pt share blk%8 (XCD).
__launch_bounds__(256, 4)
__global__ void k_dist(const short* __restrict__ Xh, const short* __restrict__ Xl,
                       const short* __restrict__ Eh, const short* __restrict__ El,
                       const float* __restrict__ e2, float* __restrict__ minv,
                       int* __restrict__ mini) {
    __shared__ __align__(16) short Ah[4096];   // [128 pts][32 k] (swizzled quads)
    __shared__ __align__(16) short Al[4096];
    __shared__ __align__(16) short Bh[4096];   // [128 codes][32 k]
    __shared__ __align__(16) short Bl[4096];
    __shared__ float sv[2][128];
    __shared__ int   si[2][128];

    const int tid = threadIdx.x;
    const int pt = blockIdx.x & 255;
    const int ct = blockIdx.x >> 8;
    const int n0 = pt * 128;
    const int c0 = ct * 128;

    const int w = tid >> 6, lane = tid & 63;
    const int wr = w >> 1, wc = w & 1;              // wave covers pts wr*64, codes wc*64
    const int m16 = lane & 15, quad = lane >> 4;

    f32x4 acc[4][4];
    #pragma unroll
    for (int i = 0; i < 4; ++i)
        #pragma unroll
        for (int j = 0; j < 4; ++j) acc[i][j] = (f32x4){0.f, 0.f, 0.f, 0.f};

    // staging: each gload16 stages 16 rows x 64B = 1KB per wave.
    // lane -> (row r = lane>>2, phys k-quad = lane&3); swizzle key s = (r>>1)&3
    // = (lane>>3)&3; this phys quad holds source logical quad (q - s) & 3.
    const int r   = lane >> 2;
    const int swz = (((lane & 3) - ((lane >> 3) & 3)) & 3) * 8;  // shorts
    const int ldsoff0 = (w * 16) * 64;        // bytes; rows w*16..
    const int ldsoff1 = (64 + w * 16) * 64;   // rows 64+w*16..
    const int arow0 = (n0 + w * 16 + r) * DIM;
    const int arow1 = (n0 + 64 + w * 16 + r) * DIM;
    const int brow0 = (c0 + w * 16 + r) * DIM;
    const int brow1 = (c0 + 64 + w * 16 + r) * DIM;

    // frag-read swizzle: phys quad = (quad + (m16>>1)) & 3  (row = i*16+m16)
    const int pq = ((quad + (m16 >> 1)) & 3) * 8;

    for (int t = 0; t < 8; ++t) {
        const int koff = t * 32 + swz;
        __syncthreads();
        gload16(Xh + arow0 + koff, (char*)Ah + ldsoff0);
        gload16(Xh + arow1 + koff, (char*)Ah + ldsoff1);
        gload16(Xl + arow0 + koff, (char*)Al + ldsoff0);
        gload16(Xl + arow1 + koff, (char*)Al + ldsoff1);
        gload16(Eh + brow0 + koff, (char*)Bh + ldsoff0);
        gload16(Eh + brow1 + koff, (char*)Bh + ldsoff1);
        gload16(El + brow0 + koff, (char*)Bl + ldsoff0);
        gload16(El + brow1 + koff, (char*)Bl + ldsoff1);
        __syncthreads();                 // compiler drains vmcnt before barrier

        short8 ah[4], al[4], bh[4], bl[4];
        #pragma unroll
        for (int i = 0; i < 4; ++i) {
            int ar = (wr * 64 + i * 16 + m16) * 32 + pq;
            ah[i] = *(const short8*)&Ah[ar];
            al[i] = *(const short8*)&Al[ar];
        }
        #pragma unroll
        for (int j = 0; j < 4; ++j) {
            int br = (wc * 64 + j * 16 + m16) * 32 + pq;
            bh[j] = *(const short8*)&Bh[br];
            bl[j] = *(const short8*)&Bl[br];
        }
        #pragma unroll
        for (int i = 0; i < 4; ++i)
            #pragma unroll
            for (int j = 0; j < 4; ++j)
                acc[i][j] = __builtin_amdgcn_mfma_f32_16x16x32_bf16(ah[i], bh[j], acc[i][j], 0, 0, 0);
        #pragma unroll
        for (int i = 0; i < 4; ++i)
            #pragma unroll
            for (int j = 0; j < 4; ++j)
                acc[i][j] = __builtin_amdgcn_mfma_f32_16x16x32_bf16(al[i], bh[j], acc[i][j], 0, 0, 0);
        #pragma unroll
        for (int i = 0; i < 4; ++i)
            #pragma unroll
            for (int j = 0; j < 4; ++j)
                acc[i][j] = __builtin_amdgcn_mfma_f32_16x16x32_bf16(ah[i], bl[j], acc[i][j], 0, 0, 0);
    }

    // dist = e2[code] - 2*dot ; C/D layout: col=lane&15 (code), row=quad*4+reg (pt)
    float ecol[4];
    #pragma unroll
    for (int j = 0; j < 4; ++j) ecol[j] = e2[c0 + wc * 64 + j * 16 + m16];

    #pragma unroll
    for (int i = 0; i < 4; ++i) {
        #pragma unroll
        for (int rr = 0; rr < 4; ++rr) {
            float best = 3.4e38f; int bi = 0;
            #pragma unroll
            for (int j = 0; j < 4; ++j) {           // j ascending -> code ascending
                float d = fmaf(-2.f, acc[i][j][rr], ecol[j]);
                int code = c0 + wc * 64 + j * 16 + m16;
                if (d < best) { best = d; bi = code; }
            }
            #pragma unroll
            for (int m = 1; m < 16; m <<= 1) {      // 16 lanes hold 16 codes of this pt
                float ov = __shfl_xor(best, m);
                int   oi = __shfl_xor(bi, m);
                if (ov < best || (ov == best && oi < bi)) { best = ov; bi = oi; }
            }
            if (m16 == 0) {
                int p = wr * 64 + i * 16 + quad * 4 + rr;
                sv[wc][p] = best; si[wc][p] = bi;
            }
        }
    }
    __syncthreads();
    if (tid < 128) {
        float v0 = sv[0][tid]; int i0 = si[0][tid];
        float v1 = sv[1][tid]; int i1 = si[1][tid];
        if (v1 < v0) { v0 = v1; i0 = i1; }          // tie -> wc0 = smaller codes
        minv[ct * NPTS + n0 + tid] = v0;
        mini[ct * NPTS + n0 + tid] = i0;
    }
}

// ---- fused: combine 8 code-tile winners + gather + write q/st/idx ----
// grid 1024 x 256; 32 points per block.
__global__ void k_out(const float* __restrict__ z, const float* __restrict__ emb,
                      const float* __restrict__ minv, const int* __restrict__ mini,
                      float* __restrict__ out) {
    __shared__ float Q[32][257];                    // [hw_local][c], pad: <=2-way banks
    __shared__ int sbi[32];
    int n0 = blockIdx.x * 32;
    int tid = threadIdx.x;
    if (tid < 32) {
        int n = n0 + tid;
        float bv = minv[n]; int bi = mini[n];
        #pragma unroll
        for (int g = 1; g < 8; ++g) {
            float v = minv[g * NPTS + n]; int ii = mini[g * NPTS + n];
            if (v < bv) { bv = v; bi = ii; }        // ascending groups -> first-min
        }
        sbi[tid] = bi;
        out[2 * QSZ + n] = (float)bi;               // idx as float
    }
    __syncthreads();
    {   // gather: 8 lanes x float4 cover one emb row 128B-contiguous per j
        int pt = tid >> 3, co = tid & 7;
        const float* ep = emb + sbi[pt] * DIM;
        #pragma unroll
        for (int j = 0; j < 8; ++j) {
            int c = j * 32 + co * 4;
            float4 v = *reinterpret_cast<const float4*>(ep + c);
            Q[pt][c] = v.x; Q[pt][c + 1] = v.y; Q[pt][c + 2] = v.z; Q[pt][c + 3] = v.w;
        }
    }
    __syncthreads();
    int hq = tid & 7, cr = tid >> 3;
    int b = n0 >> 10, hw0 = (n0 & 1023) + hq * 4;
    #pragma unroll
    for (int it = 0; it < 8; ++it) {
        int c = it * 32 + cr;
        int off = b * CHW + c * HWSZ + hw0;
        float4 zv = *reinterpret_cast<const float4*>(z + off);
        float4 q = make_float4(Q[hq * 4 + 0][c], Q[hq * 4 + 1][c],
                               Q[hq * 4 + 2][c], Q[hq * 4 + 3][c]);
        *reinterpret_cast<float4*>(out + off) = q;
        float4 st = make_float4((q.x - zv.x) + zv.x, (q.y - zv.y) + zv.y,
                                (q.z - zv.z) + zv.z, (q.w - zv.w) + zv.w);
        *reinterpret_cast<float4*>(out + QSZ + off) = st;
    }
}

extern "C" void kernel_launch(void* const* d_in, const int* in_sizes, int n_in,
                              void* d_out, int out_size, void* d_ws, size_t ws_size,
                              hipStream_t stream) {
    const float* z   = (const float*)d_in[0];
    const float* emb = (const float*)d_in[1];
    float* out = (float*)d_out;
    float* ws  = (float*)d_ws;

    // ws layout (floats): Eh[0,131072) El[131072,262144) e2[262144,263168)
    //                     minv[263168,525312) mini[525312,787456)
    short* Eh   = (short*)ws;
    short* El   = (short*)(ws + 131072);
    float* e2   = ws + 262144;
    float* minv = ws + 263168;
    int*   mini = (int*)(ws + 525312);

    // big X arrays live in d_out's q/st region (fully overwritten by k_out later)
    short* Xh = (short*)out;                 // 16.8 MB
    short* Xl = (short*)(out + 4194304);     // 16.8 MB

    hipLaunchKernelGGL(k_prep, dim3(1280), dim3(256), 0, stream, z, emb, Xh, Xl, Eh, El, e2);
    hipLaunchKernelGGL(k_dist, dim3(2048), dim3(256), 0, stream, Xh, Xl, Eh, El, e2, minv, mini);
    hipLaunchKernelGGL(k_out,  dim3(1024), dim3(256), 0, stream, z, emb, minv, mini, out);
}